// Round 4
// baseline (313.555 us; speedup 1.0000x reference)
//
#include <hip/hip_runtime.h>
#include <stdint.h>

#define NB 8
#define NPRED 25200
#define NTOP 1000
#define NCLS 80
#define CONF_T 0.25f
#define IOU_THR 0.45f
#define MAXWH 4096.0f
#define CAP 2048
#define NBINS 1025
#define SBLK 128
#define SBPB 197   // ceil(25200/128): 197*128 = 25216

typedef unsigned long long u64;

// ---------------------------------------------------------------------------
// K1: score/class per pred + global histogram of score bits.
// Staging via global_load_lds width=16 (no VGPR round trip).
// ---------------------------------------------------------------------------
__global__ __launch_bounds__(128) void k_score(const float* __restrict__ x,
                                               float* __restrict__ msc,
                                               int* __restrict__ cls,
                                               unsigned* __restrict__ hist) {
#pragma clang fp contract(off)
    __shared__ __align__(16) float sm[SBLK * 85];
    const int b = blockIdx.x / SBPB;
    const int blk = blockIdx.x % SBPB;
    const int t = threadIdx.x;
    const int wave = t >> 6, lane = t & 63;
    const long long TOT4 = (long long)NB * NPRED * 85 / 4;  // 4,284,000
    const long long base4 = ((long long)b * NPRED + (long long)blk * SBLK) * 85 / 4;
    const float4* x4 = (const float4*)x;
    const int tile4 = SBLK * 85 / 4;  // 2720

    for (int k = 0; k < 22; ++k) {
        int ib = k * 128 + wave * 64;      // wave-uniform lds base (float4 units)
        int fi = ib + lane;
        if (fi < tile4) {
            long long gi = base4 + fi;
            if (gi >= TOT4) gi = TOT4 - 1;  // tail clamp (outputs guarded below)
            __builtin_amdgcn_global_load_lds(
                (const __attribute__((address_space(1))) void*)(x4 + gi),
                (__attribute__((address_space(3))) void*)(sm + (size_t)ib * 4),
                16, 0, 0);
        }
    }
    __syncthreads();

    int pred = blk * SBLK + t;
    if (pred < NPRED) {
        const float* p = &sm[t * 85];
        float obj = p[4];
        float best = p[5];
        int bid = 0;
        for (int c = 1; c < NCLS; ++c) {
            float v = p[5 + c];
            if (v > best) { best = v; bid = c; }  // strict >: first occurrence
        }
        float score = obj * best;
        int q = b * NPRED + pred;
        msc[q] = (score > CONF_T) ? score : -1.0f;
        cls[q] = bid;
        if (score > CONF_T) {
            int bin = (int)(__float_as_uint(score) >> 14) - 0xFA00;
            bin = bin < 0 ? 0 : (bin > 1024 ? 1024 : bin);
            atomicAdd(&hist[b * NBINS + bin], 1u);
        }
    }
}

// ---------------------------------------------------------------------------
// K2 (fused): per-batch boundary-bin + compact-into-LDS + bitonic sort of
// <=2048 candidates (512 threads, 2 CE/thread) + gather top-1000.
// Key = (~score_bits << 32) | idx : ascending sort = descending score,
// ascending index on ties (stable top_k semantics).
// ---------------------------------------------------------------------------
__global__ __launch_bounds__(512) void k_sort(const float* __restrict__ x,
                                              const float* __restrict__ msc,
                                              const int* __restrict__ cls,
                                              const unsigned* __restrict__ hist,
                                              float* __restrict__ det,
                                              float* __restrict__ offb,
                                              unsigned* __restrict__ valid) {
#pragma clang fp contract(off)
    __shared__ u64 keys[CAP];
    __shared__ int sB;
    __shared__ unsigned lcnt;
    const int b = blockIdx.x, t = threadIdx.x;
    const float* ms = msc + (size_t)b * NPRED;

    if (t == 0) lcnt = 0;
    if (t < 64) {  // wave 0: suffix-count boundary bin B
        const int lane = t;
        const unsigned* h = hist + b * NBINS;
        const int hi2 = 1024 - 16 * lane;       // lane chunk: bins [hi2-15, hi2]
        unsigned sum = 0;
        for (int k = 0; k < 16; ++k) sum += h[hi2 - k];
        if (lane == 63) sum += h[0];
        unsigned v = sum;
        for (int d = 1; d < 64; d <<= 1) {
            unsigned o = __shfl_up(v, d);
            if (lane >= d) v += o;
        }
        unsigned excl = v - sum;                // count strictly above my chunk
        u64 ball = __ballot(v >= NTOP);
        int B = 0;
        if (ball != 0) {
            int sel = __builtin_ctzll(ball);
            if (lane == sel) {
                unsigned run = excl;
                for (int k = 0; k < 16; ++k) {
                    run += h[hi2 - k];
                    if (run >= NTOP) { B = hi2 - k; break; }
                }
            }
            B = __shfl(B, sel);
        }
        if (lane == 0) sB = B;
    }
    __syncthreads();
    const int B = sB;

    // compact candidates (bin >= B) into LDS
    for (int p = t; p < NPRED; p += 512) {
        float s = ms[p];
        if (s > CONF_T) {
            unsigned bits = __float_as_uint(s);
            int bin = (int)(bits >> 14) - 0xFA00;
            bin = bin < 0 ? 0 : (bin > 1024 ? 1024 : bin);
            if (bin >= B) {
                unsigned slot = atomicAdd(&lcnt, 1u);
                if (slot < CAP)
                    keys[slot] = ((u64)(~bits) << 32) | (unsigned)p;
            }
        }
    }
    __syncthreads();
    unsigned c = lcnt; if (c > CAP) c = CAP;
    for (int i = (int)c + t; i < CAP; i += 512) keys[i] = ~0ULL;
    __syncthreads();

    // bitonic sort CAP keys ascending; 2 compare-exchanges per thread per round
    for (unsigned k = 2; k <= CAP; k <<= 1) {
        for (unsigned j = k >> 1; j > 0; j >>= 1) {
#pragma unroll
            for (int half = 0; half < 2; ++half) {
                unsigned tt = (unsigned)t + half * 512;
                unsigned i = ((tt & ~(j - 1)) << 1) | (tt & (j - 1));
                unsigned pi = i | j;
                bool up = ((i & k) == 0);
                u64 a = keys[i], d = keys[pi];
                bool sw = up ? (a > d) : (a < d);
                if (sw) { keys[i] = d; keys[pi] = a; }
            }
            __syncthreads();
        }
    }

    // gather top-1000 -> det rows, class-offset boxes, valid flags
    for (int r = t; r < NTOP; r += 512) {
        u64 key = keys[r];
        unsigned p = (unsigned)key;
        float score = __uint_as_float(~(unsigned)(key >> 32));
        bool v = score > CONF_T;
        float o0 = 0, o1 = 0, o2 = 0, o3 = 0, o4 = 0, o5 = 0;
        float f0 = 0, f1 = 0, f2 = 0, f3 = 0;
        if (v) {
            const float* xp = x + ((size_t)b * NPRED + p) * 85;
            float xc = xp[0], yc = xp[1], w = xp[2], h = xp[3];
            float hw = w * 0.5f, hh = h * 0.5f;
            o0 = xc - hw; o1 = yc - hh; o2 = xc + hw; o3 = yc + hh;
            o4 = score;
            float cf = (float)cls[(size_t)b * NPRED + p];
            o5 = cf;
            float co = cf * MAXWH;
            f0 = o0 + co; f1 = o1 + co; f2 = o2 + co; f3 = o3 + co;
        }
        size_t d6 = ((size_t)b * NTOP + r) * 6;
        det[d6 + 0] = o0; det[d6 + 1] = o1; det[d6 + 2] = o2;
        det[d6 + 3] = o3; det[d6 + 4] = o4; det[d6 + 5] = o5;
        size_t d4 = ((size_t)b * NTOP + r) * 4;
        offb[d4 + 0] = f0; offb[d4 + 1] = f1; offb[d4 + 2] = f2; offb[d4 + 3] = f3;
        valid[(size_t)b * NTOP + r] = v ? 1u : 0u;
    }
}

// ---------------------------------------------------------------------------
// K3: 1000x1000 IoU bitmask. Lanes <-> consecutive rows; columns are
// broadcast LDS reads (conflict-free). grid = 8 batches x 32 row-groups.
// ---------------------------------------------------------------------------
__global__ __launch_bounds__(256) void k_iou(const float* __restrict__ offb,
                                             u64* __restrict__ mask) {
#pragma clang fp contract(off)
    __shared__ __align__(16) float4 bx4[NTOP];
    __shared__ float area[NTOP];
    const int b = blockIdx.x >> 5;
    const int rg = blockIdx.x & 31;
    const float4* ob = (const float4*)(offb + (size_t)b * NTOP * 4);
    for (int i = threadIdx.x; i < NTOP; i += 256) {
        float4 v = ob[i];
        bx4[i] = v;
        area[i] = (v.z - v.x) * (v.w - v.y);
    }
    __syncthreads();
    const int i = rg * 32 + (threadIdx.x & 31);
    const int q = threadIdx.x >> 5;            // 8 word-pairs
    if (i >= NTOP) return;
    float4 A = bx4[i];
    float areaA = area[i];
    u64* mrow = &mask[((size_t)b * NTOP + i) * 16];
    for (int wi = 0; wi < 2; ++wi) {
        int w = q * 2 + wi;
        u64 bits = 0;
        int c0 = w * 64;
        for (int cc = 0; cc < 64; ++cc) {
            int col = c0 + cc;
            if (col >= NTOP) break;
            float4 Bb = bx4[col];              // broadcast read
            float ltx = fmaxf(A.x, Bb.x), lty = fmaxf(A.y, Bb.y);
            float rbx = fminf(A.z, Bb.z), rby = fminf(A.w, Bb.w);
            float ww = fmaxf(rbx - ltx, 0.0f), hh = fmaxf(rby - lty, 0.0f);
            float inter = ww * hh;
            float iou = inter / (((areaA + area[col]) - inter) + 1e-9f);
            if (iou > IOU_THR && col != i) bits |= (1ULL << cc);
        }
        mrow[w] = bits;
    }
}

// ---------------------------------------------------------------------------
// K4: serial greedy scan, one wave per batch. ALL chain state is tiny:
//  - Sdist (2 VGPRs): suppression vector distributed, lane l holds word l&15
//  - diag word per lane (prefetched 2 groups ahead, 4 VGPRs)
//  - chain runs on wave-uniform SGPRs via constant-lane v_readlane
// No per-lane mask arrays -> no scratch spill (round-3's 67 us was spill
// traffic: WRITE_SIZE 379.5 KB vs 187.5 KB of real output).
// Kept-row updates: one coalesced 128 B global load per kept row.
// ---------------------------------------------------------------------------
__global__ __launch_bounds__(64) void k_scan(const u64* __restrict__ mask,
                                             const unsigned* __restrict__ valid,
                                             const float* __restrict__ det,
                                             float* __restrict__ out) {
    const int b = blockIdx.x;
    const int lane = threadIdx.x;
    const u64* mb = mask + (size_t)b * NTOP * 16;
    __shared__ u64 kbs[16];

    // valid ballots (wave-uniform -> SGPRs)
    u64 vbs[16];
#pragma unroll
    for (int g = 0; g < 16; ++g) {
        int r = g * 64 + lane;
        unsigned vf = (r < NTOP) ? valid[(size_t)b * NTOP + r] : 0u;
        vbs[g] = __ballot(vf != 0);
    }

    // diag-block loads: lane tt gets mask[64g+tt][g]; prefetch 2 ahead
    auto diagload = [&](int g) -> u64 {
        int r = g * 64 + lane;
        if (r > NTOP - 1) r = NTOP - 1;        // clamp: clamped rows have vb=0
        return mb[(size_t)r * 16 + g];
    };
    u64 dcur = diagload(0);
    u64 dnxt = diagload(1);

    u64 Sdist = 0;  // lane l holds suppression word (l & 15)

#pragma unroll
    for (int g = 0; g < 16; ++g) {
        // wave-uniform suppression word g from lane g
        int slo = __builtin_amdgcn_readlane((int)(unsigned)Sdist, g);
        int shi = __builtin_amdgcn_readlane((int)(unsigned)(Sdist >> 32), g);
        u64 S = ((u64)(unsigned)shi << 32) | (unsigned)slo;

        u64 avail = vbs[g] & ~S;               // rows still eligible
        const int mlo = (int)(unsigned)dcur;
        const int mhi = (int)(unsigned)(dcur >> 32);
        u64 kb = 0;
#pragma unroll
        for (int tt = 0; tt < 64; ++tt) {
            unsigned lo = (unsigned)__builtin_amdgcn_readlane(mlo, tt);
            unsigned hi = (unsigned)__builtin_amdgcn_readlane(mhi, tt);
            u64 m = ((u64)hi << 32) | lo;
            u64 bit = 1ULL << tt;
            bool keep = (avail & bit) != 0;
            kb |= avail & bit;                  // parallel accumulator chain
            avail &= keep ? ~m : ~0ULL;         // diag bit tt of m is 0 (ref zeroes diag)
        }
        if (lane == 0) kbs[g] = kb;

        dcur = dnxt;                            // rotate diag prefetch
        if (g + 2 < 16) dnxt = diagload(g + 2);

        // fold kept rows' full mask rows into Sdist (coalesced 128 B loads,
        // independent; single vmcnt drain before next group's readlane)
        u64 rem = kb;
        while (rem) {
            int tt = __builtin_ctzll(rem);
            rem &= rem - 1;
            int r = g * 64 + tt;
            Sdist |= mb[(size_t)r * 16 + (lane & 15)];
        }
    }

    // masked output copy: rows are 3 x float2, float2 never straddles a row
    const float2* dp2 = (const float2*)(det + (size_t)b * NTOP * 6);
    float2* op2 = (float2*)(out + (size_t)b * NTOP * 6);
    for (int e = lane; e < NTOP * 3; e += 64) {
        int r = e / 3;
        u64 kb = kbs[r >> 6];
        bool keep = (kb >> (r & 63)) & 1ULL;
        float2 v = dp2[e];
        float2 z;
        z.x = keep ? v.x : 0.0f;
        z.y = keep ? v.y : 0.0f;
        op2[e] = z;
    }
}

// ---------------------------------------------------------------------------
extern "C" void kernel_launch(void* const* d_in, const int* in_sizes, int n_in,
                              void* d_out, int out_size, void* d_ws, size_t ws_size,
                              hipStream_t stream) {
    const float* x = (const float*)d_in[0];
    char* ws = (char*)d_ws;
    // layout (bytes):
    float* msc = (float*)(ws);                       //       0 .. 806400
    int* cls = (int*)(ws + 806400);                  //  806400 .. 1612800
    float* det = (float*)(ws + 1612800);             // 1612800 .. 1804800
    float* offb = (float*)(ws + 1804800);            // 1804800 .. 1932800
    unsigned* valid = (unsigned*)(ws + 1932800);     // 1932800 .. 1964800
    u64* mask = (u64*)(ws + 1964800);                // 1964800 .. 2988800
    // hist overlays the mask region (consumed by k_sort before k_iou writes):
    unsigned* hist = (unsigned*)(ws + 1964800);      // 8*1025*4 = 32800

    hipMemsetAsync(hist, 0, 32800, stream);
    k_score<<<NB * SBPB, 128, 0, stream>>>(x, msc, cls, hist);
    k_sort<<<NB, 512, 0, stream>>>(x, msc, cls, hist, det, offb, valid);
    k_iou<<<NB * 32, 256, 0, stream>>>(offb, mask);
    k_scan<<<NB, 64, 0, stream>>>(mask, valid, det, (float*)d_out);
}

// Round 5
// 249.021 us; speedup vs baseline: 1.2592x; 1.2592x over previous
//
#include <hip/hip_runtime.h>
#include <stdint.h>

#define NB 8
#define NPRED 25200
#define NTOP 1000
#define NCLS 80
#define CONF_T 0.25f
#define IOU_THR 0.45f
#define MAXWH 4096.0f
#define CAP 2048
#define NBINS 1025
#define SBLK 128
#define SBPB 197   // ceil(25200/128): 197*128 = 25216

typedef unsigned long long u64;

// ---------------------------------------------------------------------------
// K1: score/class per pred + global histogram of score bits.
// Staging via global_load_lds width=16 (no VGPR round trip).
// ---------------------------------------------------------------------------
__global__ __launch_bounds__(128) void k_score(const float* __restrict__ x,
                                               float* __restrict__ msc,
                                               int* __restrict__ cls,
                                               unsigned* __restrict__ hist) {
#pragma clang fp contract(off)
    __shared__ __align__(16) float sm[SBLK * 85];
    const int b = blockIdx.x / SBPB;
    const int blk = blockIdx.x % SBPB;
    const int t = threadIdx.x;
    const int wave = t >> 6, lane = t & 63;
    const long long TOT4 = (long long)NB * NPRED * 85 / 4;  // 4,284,000
    const long long base4 = ((long long)b * NPRED + (long long)blk * SBLK) * 85 / 4;
    const float4* x4 = (const float4*)x;
    const int tile4 = SBLK * 85 / 4;  // 2720

    for (int k = 0; k < 22; ++k) {
        int ib = k * 128 + wave * 64;      // wave-uniform lds base (float4 units)
        int fi = ib + lane;
        if (fi < tile4) {
            long long gi = base4 + fi;
            if (gi >= TOT4) gi = TOT4 - 1;  // tail clamp (outputs guarded below)
            __builtin_amdgcn_global_load_lds(
                (const __attribute__((address_space(1))) void*)(x4 + gi),
                (__attribute__((address_space(3))) void*)(sm + (size_t)ib * 4),
                16, 0, 0);
        }
    }
    __syncthreads();

    int pred = blk * SBLK + t;
    if (pred < NPRED) {
        const float* p = &sm[t * 85];
        float obj = p[4];
        float best = p[5];
        int bid = 0;
        for (int c = 1; c < NCLS; ++c) {
            float v = p[5 + c];
            if (v > best) { best = v; bid = c; }  // strict >: first occurrence
        }
        float score = obj * best;
        int q = b * NPRED + pred;
        msc[q] = (score > CONF_T) ? score : -1.0f;
        cls[q] = bid;
        if (score > CONF_T) {
            int bin = (int)(__float_as_uint(score) >> 14) - 0xFA00;
            bin = bin < 0 ? 0 : (bin > 1024 ? 1024 : bin);
            atomicAdd(&hist[b * NBINS + bin], 1u);
        }
    }
}

// ---------------------------------------------------------------------------
// K2: per-batch boundary bin B (suffix count >= 1000). 8 waves, wave = batch.
// ---------------------------------------------------------------------------
__global__ __launch_bounds__(512) void k_boundary(const unsigned* __restrict__ hist,
                                                  int* __restrict__ Bv) {
    int b = threadIdx.x >> 6, lane = threadIdx.x & 63;
    const unsigned* h = hist + b * NBINS;
    int hi = 1024 - 16 * lane;           // lane chunk: bins [hi-15, hi]
    unsigned sum = 0;
    for (int k = 0; k < 16; ++k) sum += h[hi - k];
    if (lane == 63) sum += h[0];
    unsigned v = sum;
    for (int d = 1; d < 64; d <<= 1) {
        unsigned o = __shfl_up(v, d);
        if (lane >= d) v += o;
    }
    unsigned excl = v - sum;             // count strictly above my chunk
    u64 ball = __ballot(v >= NTOP);
    int B = 0;
    if (ball != 0) {
        int sel = __builtin_ctzll(ball);
        if (lane == sel) {
            unsigned run = excl;
            for (int k = 0; k < 16; ++k) {
                run += h[hi - k];
                if (run >= NTOP) { B = hi - k; break; }
            }
        }
        B = __shfl(B, sel);
    }
    if (lane == 0) Bv[b] = B;
}

// ---------------------------------------------------------------------------
// K3: compact candidates (bin >= B), one pred per thread (200 wide blocks).
// ---------------------------------------------------------------------------
__global__ __launch_bounds__(1024) void k_compact(const float* __restrict__ msc,
                                                  const int* __restrict__ Bv,
                                                  unsigned* __restrict__ cnt,
                                                  u64* __restrict__ cand) {
    int b = blockIdx.x / 25;
    int p = (blockIdx.x % 25) * 1024 + threadIdx.x;
    if (p >= NPRED) return;
    float s = msc[(size_t)b * NPRED + p];
    if (s > CONF_T) {
        unsigned bits = __float_as_uint(s);
        int bin = (int)(bits >> 14) - 0xFA00;
        bin = bin < 0 ? 0 : (bin > 1024 ? 1024 : bin);
        if (bin >= Bv[b]) {
            unsigned slot = atomicAdd(&cnt[b], 1u);
            if (slot < CAP)
                cand[(size_t)b * CAP + slot] = ((u64)(~bits) << 32) | (unsigned)p;
        }
    }
}

// ---------------------------------------------------------------------------
// K4: per-batch bitonic sort of <=2048 candidates (512 threads, 2 CE each)
// + gather top-1000. Key = (~score_bits << 32) | idx.
// ---------------------------------------------------------------------------
__global__ __launch_bounds__(512) void k_sort(const float* __restrict__ x,
                                              const int* __restrict__ cls,
                                              const unsigned* __restrict__ cnt,
                                              const u64* __restrict__ cand,
                                              float* __restrict__ det,
                                              float* __restrict__ offb,
                                              unsigned* __restrict__ valid) {
#pragma clang fp contract(off)
    __shared__ u64 keys[CAP];
    const int b = blockIdx.x, t = threadIdx.x;
    unsigned c = cnt[b]; if (c > CAP) c = CAP;
    for (int i = t; i < CAP; i += 512)
        keys[i] = (i < (int)c) ? cand[(size_t)b * CAP + i] : ~0ULL;
    __syncthreads();

    for (unsigned k = 2; k <= CAP; k <<= 1) {
        for (unsigned j = k >> 1; j > 0; j >>= 1) {
#pragma unroll
            for (int half = 0; half < 2; ++half) {
                unsigned tt = (unsigned)t + half * 512;
                unsigned i = ((tt & ~(j - 1)) << 1) | (tt & (j - 1));
                unsigned pi = i | j;
                bool up = ((i & k) == 0);
                u64 a = keys[i], d = keys[pi];
                bool sw = up ? (a > d) : (a < d);
                if (sw) { keys[i] = d; keys[pi] = a; }
            }
            __syncthreads();
        }
    }

    for (int r = t; r < NTOP; r += 512) {
        u64 key = keys[r];
        unsigned p = (unsigned)key;
        float score = __uint_as_float(~(unsigned)(key >> 32));
        bool v = score > CONF_T;
        float o0 = 0, o1 = 0, o2 = 0, o3 = 0, o4 = 0, o5 = 0;
        float f0 = 0, f1 = 0, f2 = 0, f3 = 0;
        if (v) {
            const float* xp = x + ((size_t)b * NPRED + p) * 85;
            float xc = xp[0], yc = xp[1], w = xp[2], h = xp[3];
            float hw = w * 0.5f, hh = h * 0.5f;
            o0 = xc - hw; o1 = yc - hh; o2 = xc + hw; o3 = yc + hh;
            o4 = score;
            float cf = (float)cls[(size_t)b * NPRED + p];
            o5 = cf;
            float co = cf * MAXWH;
            f0 = o0 + co; f1 = o1 + co; f2 = o2 + co; f3 = o3 + co;
        }
        size_t d6 = ((size_t)b * NTOP + r) * 6;
        det[d6 + 0] = o0; det[d6 + 1] = o1; det[d6 + 2] = o2;
        det[d6 + 3] = o3; det[d6 + 4] = o4; det[d6 + 5] = o5;
        size_t d4 = ((size_t)b * NTOP + r) * 4;
        offb[d4 + 0] = f0; offb[d4 + 1] = f1; offb[d4 + 2] = f2; offb[d4 + 3] = f3;
        valid[(size_t)b * NTOP + r] = v ? 1u : 0u;
    }
}

// ---------------------------------------------------------------------------
// K5: 1000x1000 IoU bitmask, stored TRANSPOSED: maskT[b][w][i] = word w
// (columns 64w..64w+63) of row i. Coalesced writes here, coalesced row
// loads in k_scan. grid = 8 batches x 32 row-groups.
// ---------------------------------------------------------------------------
__global__ __launch_bounds__(256) void k_iou(const float* __restrict__ offb,
                                             u64* __restrict__ maskT) {
#pragma clang fp contract(off)
    __shared__ __align__(16) float4 bx4[NTOP];
    __shared__ float area[NTOP];
    const int b = blockIdx.x >> 5;
    const int rg = blockIdx.x & 31;
    const float4* ob = (const float4*)(offb + (size_t)b * NTOP * 4);
    for (int i = threadIdx.x; i < NTOP; i += 256) {
        float4 v = ob[i];
        bx4[i] = v;
        area[i] = (v.z - v.x) * (v.w - v.y);
    }
    __syncthreads();
    const int i = rg * 32 + (threadIdx.x & 31);
    const int q = threadIdx.x >> 5;            // 8 word-pairs
    if (i >= NTOP) return;
    float4 A = bx4[i];
    float areaA = area[i];
    u64* mt = maskT + (size_t)b * 16 * NTOP;
    for (int wi = 0; wi < 2; ++wi) {
        int w = q * 2 + wi;
        u64 bits = 0;
        int c0 = w * 64;
        for (int cc = 0; cc < 64; ++cc) {
            int col = c0 + cc;
            if (col >= NTOP) break;
            float4 Bb = bx4[col];              // broadcast read
            float ltx = fmaxf(A.x, Bb.x), lty = fmaxf(A.y, Bb.y);
            float rbx = fminf(A.z, Bb.z), rby = fminf(A.w, Bb.w);
            float ww = fmaxf(rbx - ltx, 0.0f), hh = fmaxf(rby - lty, 0.0f);
            float inter = ww * hh;
            float iou = inter / (((areaA + area[col]) - inter) + 1e-9f);
            if (iou > IOU_THR && col != i) bits |= (1ULL << cc);
        }
        mt[(size_t)w * NTOP + i] = bits;       // transposed, coalesced in i
    }
}

// ---------------------------------------------------------------------------
// K6: serial greedy scan, one wave per batch. SYMMETRY TRICK: iou is
// bit-exactly symmetric, so row c's suppression bit = (mask_row_c & Kept)!=0.
// Each lane owns its row (16 u64, prefetched one group ahead, coalesced via
// transposed layout); Kept vector Kp[16] is wave-uniform SALU state updated
// with one OR per group. ZERO loads on the serial path (round-4's 148 us was
// ~900 serial per-keep global loads).
// ---------------------------------------------------------------------------
__global__ __launch_bounds__(64) void k_scan(const u64* __restrict__ maskT,
                                             const unsigned* __restrict__ valid,
                                             const float* __restrict__ det,
                                             float* __restrict__ out) {
    const int b = blockIdx.x;
    const int lane = threadIdx.x;
    const u64* mt = maskT + (size_t)b * 16 * NTOP;
    __shared__ u64 kbs[16];

    u64 cur[16], nxt[16];
    unsigned vcur = 0, vnxt = 0;

    {   // load group 0
        int r = lane;  // < NTOP always
#pragma unroll
        for (int w = 0; w < 16; ++w) cur[w] = mt[(size_t)w * NTOP + r];
        vcur = valid[(size_t)b * NTOP + r];
    }

    u64 Kp[16];
#pragma unroll
    for (int w = 0; w < 16; ++w) Kp[w] = 0;

#pragma unroll
    for (int g = 0; g < 16; ++g) {
        if (g + 1 < 16) {   // prefetch next group (coalesced 512 B per word)
            int r = (g + 1) * 64 + lane;
            int rc = r < NTOP ? r : NTOP - 1;
#pragma unroll
            for (int w = 0; w < 16; ++w) nxt[w] = mt[(size_t)w * NTOP + rc];
            vnxt = (r < NTOP) ? valid[(size_t)b * NTOP + r] : 0u;
        }

        // pre-suppression from earlier groups via symmetry: row & Kept
        u64 hit = 0;
#pragma unroll
        for (int w = 0; w < 16; ++w) hit |= cur[w] & Kp[w];
        u64 preS = __ballot(hit != 0ULL);
        u64 vb = __ballot(vcur != 0u);

        // intra-group serial chain on wave-uniform state (SALU + readlane)
        u64 avail = vb & ~preS;
        const int mlo = (int)(unsigned)cur[g];
        const int mhi = (int)(unsigned)(cur[g] >> 32);
        u64 kb = 0;
#pragma unroll
        for (int tt = 0; tt < 64; ++tt) {
            unsigned lo = (unsigned)__builtin_amdgcn_readlane(mlo, tt);
            unsigned hi = (unsigned)__builtin_amdgcn_readlane(mhi, tt);
            u64 m = ((u64)hi << 32) | lo;
            u64 bit = 1ULL << tt;
            kb |= avail & bit;
            avail &= ((avail & bit) != 0ULL) ? ~m : ~0ULL;
        }
        if (lane == 0) kbs[g] = kb;
        Kp[g] |= kb;                        // one SALU op; no loads

#pragma unroll
        for (int w = 0; w < 16; ++w) cur[w] = nxt[w];
        vcur = vnxt;
    }
    __syncthreads();

    // masked output copy: rows are 3 x float2, float2 never straddles a row
    const float2* dp2 = (const float2*)(det + (size_t)b * NTOP * 6);
    float2* op2 = (float2*)(out + (size_t)b * NTOP * 6);
    for (int e = lane; e < NTOP * 3; e += 64) {
        int r = e / 3;
        u64 kb = kbs[r >> 6];
        bool keep = (kb >> (r & 63)) & 1ULL;
        float2 v = dp2[e];
        float2 z;
        z.x = keep ? v.x : 0.0f;
        z.y = keep ? v.y : 0.0f;
        op2[e] = z;
    }
}

// ---------------------------------------------------------------------------
extern "C" void kernel_launch(void* const* d_in, const int* in_sizes, int n_in,
                              void* d_out, int out_size, void* d_ws, size_t ws_size,
                              hipStream_t stream) {
    const float* x = (const float*)d_in[0];
    char* ws = (char*)d_ws;
    // layout (bytes):
    float* msc = (float*)(ws);                       //       0 .. 806400
    int* cls = (int*)(ws + 806400);                  //  806400 .. 1612800
    float* det = (float*)(ws + 1612800);             // 1612800 .. 1804800
    float* offb = (float*)(ws + 1804800);            // 1804800 .. 1932800
    unsigned* valid = (unsigned*)(ws + 1932800);     // 1932800 .. 1964800
    u64* maskT = (u64*)(ws + 1964800);               // 1964800 .. 2988800
    // overlays in mask region (all consumed before k_iou writes maskT):
    unsigned* hist = (unsigned*)(ws + 1964800);      // 32800
    unsigned* cnt = (unsigned*)(ws + 1997600);       // 32
    int* Bv = (int*)(ws + 1997632);                  // 32
    u64* cand = (u64*)(ws + 1997664);                // 131072

    hipMemsetAsync(hist, 0, 32864, stream);          // hist + cnt + Bv
    k_score<<<NB * SBPB, 128, 0, stream>>>(x, msc, cls, hist);
    k_boundary<<<1, 512, 0, stream>>>(hist, Bv);
    k_compact<<<NB * 25, 1024, 0, stream>>>(msc, Bv, cnt, cand);
    k_sort<<<NB, 512, 0, stream>>>(x, cls, cnt, cand, det, offb, valid);
    k_iou<<<NB * 32, 256, 0, stream>>>(offb, maskT);
    k_scan<<<NB, 64, 0, stream>>>(maskT, valid, det, (float*)d_out);
}